// Round 16
// baseline (113.044 us; speedup 1.0000x reference)
//
#include <hip/hip_runtime.h>
#include <float.h>

#define NT 32768
#define DIM 2048
#define NE 64
#define TAU 1e-3f
#define CHUNK 64
#define NCH (DIM / CHUNK)   // 32 chunks

typedef __attribute__((ext_vector_type(8))) short short8;
typedef __attribute__((ext_vector_type(4))) float f32x4;

__device__ __forceinline__ unsigned short f2bf(float f) {
    unsigned u = __float_as_uint(f);
    u += 0x7fffu + ((u >> 16) & 1u);          // RNE
    return (unsigned short)(u >> 16);
}
__device__ __forceinline__ float bf2f(unsigned short h) {
    return __uint_as_float(((unsigned)h) << 16);
}

// Pack gw into MFMA-B fragment order, split hi/lo bf16 (RNE):
// wpk[et][ksg][lane][j] = gw[et*16 + (lane&15)][ksg*32 + (lane>>4)*8 + j]
__global__ __launch_bounds__(256)
void prep_w(const float* __restrict__ gw, unsigned short* __restrict__ wph,
            unsigned short* __restrict__ wpl, int* __restrict__ cnt) {
    const int gid  = blockIdx.x * 256 + threadIdx.x;   // 16384 threads
    const int lane = gid & 63;
    const int ksg  = (gid >> 6) & 63;
    const int et   = gid >> 12;
    const int e    = et * 16 + (lane & 15);
    const int k0   = ksg * 32 + (lane >> 4) * 8;

    float4 v0 = *(const float4*)(gw + (size_t)e * DIM + k0);
    float4 v1 = *(const float4*)(gw + (size_t)e * DIM + k0 + 4);
    float xf[8] = {v0.x, v0.y, v0.z, v0.w, v1.x, v1.y, v1.z, v1.w};
    short8 h, l;
#pragma unroll
    for (int j = 0; j < 8; ++j) {
        unsigned short hh = f2bf(xf[j]);
        h[j] = (short)hh;
        l[j] = (short)f2bf(xf[j] - bf2f(hh));
    }
    *(short8*)(wph + (size_t)gid * 8) = h;
    *(short8*)(wpl + (size_t)gid * 8) = l;
    if (gid == 0) *cnt = 0;
}

__global__ __launch_bounds__(256, 4)
void router_mfma(const float* __restrict__ x,
                 const unsigned short* __restrict__ wph,
                 const unsigned short* __restrict__ wpl,
                 float* __restrict__ out,
                 int* __restrict__ cnt, int* __restrict__ list) {
    // 32 KB: 2 dbuf x {hi 8K, lo 8K} bf16 [64 tok][64 k]; epilogue aliases lm[64][68]
    __shared__ __align__(16) unsigned char smem[32768];

    const int tid  = threadIdx.x;
    const int lane = tid & 63;
    const int et   = tid >> 6;                 // wave == 16-expert tile
    const int t0   = blockIdx.x * 64;

    // staging: thread -> row r = tid&63, k-octet pair o = tid>>6 (16 floats)
    const int srow = tid & 63;
    const int so   = tid >> 6;
    const unsigned sw0 = (unsigned)(srow * 128 + (((2 * so)     ^ (srow & 7)) << 4));
    const unsigned sw1 = (unsigned)(srow * 128 + (((2 * so + 1) ^ (srow & 7)) << 4));
    const float* xrow = x + (size_t)(t0 + srow) * DIM + so * 16;

    // compute-side read offsets: row = tt*16 + (lane&15); slot = (kg*4+(lane>>4)) ^ (lane&7)
    unsigned rbase[4], koff[2];
#pragma unroll
    for (int tt = 0; tt < 4; ++tt)
        rbase[tt] = (unsigned)((tt * 16 + (lane & 15)) * 128);
#pragma unroll
    for (int kg = 0; kg < 2; ++kg)
        koff[kg] = (unsigned)(((kg * 4 + (lane >> 4)) ^ (lane & 7)) << 4);

    f32x4 accP[4], accQ[4];
#pragma unroll
    for (int tt = 0; tt < 4; ++tt)
#pragma unroll
        for (int j = 0; j < 4; ++j) { accP[tt][j] = 0.f; accQ[tt][j] = 0.f; }

    float4 xr[4];                              // 16 floats staged per thread
    short8 Bh[2], Bl[2];                       // JIT per chunk

#define LOADX(c_) { _Pragma("unroll") for (int i = 0; i < 4; ++i) \
        xr[i] = *(const float4*)(xrow + (c_) * CHUNK + i * 4); }

#define BLOAD(c_) { _Pragma("unroll") for (int kg = 0; kg < 2; ++kg) { \
        size_t o_ = (((size_t)et * 64 + ((c_) * 2 + kg)) * 64 + lane) * 8; \
        Bh[kg] = *(const short8*)(wph + o_); \
        Bl[kg] = *(const short8*)(wpl + o_); } }

// truncation split: hi = top16(x), lo = top16(x - hi); write 2x16B hi + 2x16B lo
#define CVT_STORE(buf_) { \
        _Pragma("unroll") for (int p = 0; p < 2; ++p) { \
            float4 a_ = xr[2*p], b_ = xr[2*p+1]; \
            float f_[8] = {a_.x, a_.y, a_.z, a_.w, b_.x, b_.y, b_.z, b_.w}; \
            unsigned short hh[8], ll[8]; \
            _Pragma("unroll") for (int j = 0; j < 8; ++j) { \
                unsigned u_ = __float_as_uint(f_[j]); \
                hh[j] = (unsigned short)(u_ >> 16); \
                float lo_ = f_[j] - __uint_as_float(u_ & 0xffff0000u); \
                ll[j] = (unsigned short)(__float_as_uint(lo_) >> 16); } \
            unsigned char* p0_ = smem + (buf_) * 16384 + (p ? sw1 : sw0); \
            *(ushort4*)p0_ = make_ushort4(hh[0], hh[1], hh[2], hh[3]); \
            *(ushort4*)(p0_ + 8) = make_ushort4(hh[4], hh[5], hh[6], hh[7]); \
            *(ushort4*)(p0_ + 8192) = make_ushort4(ll[0], ll[1], ll[2], ll[3]); \
            *(ushort4*)(p0_ + 8200) = make_ushort4(ll[4], ll[5], ll[6], ll[7]); } }

#define MFMA_PHASE(buf_) { _Pragma("unroll") for (int kg = 0; kg < 2; ++kg) \
    _Pragma("unroll") for (int tt = 0; tt < 4; ++tt) { \
        const unsigned char* pa_ = smem + (buf_) * 16384 + rbase[tt] + koff[kg]; \
        short8 Ah_ = *(const short8*)pa_; \
        short8 Al_ = *(const short8*)(pa_ + 8192); \
        accP[tt] = __builtin_amdgcn_mfma_f32_16x16x32_bf16(Ah_, Bh[kg], accP[tt], 0, 0, 0); \
        accQ[tt] = __builtin_amdgcn_mfma_f32_16x16x32_bf16(Ah_, Bl[kg], accQ[tt], 0, 0, 0); \
        accQ[tt] = __builtin_amdgcn_mfma_f32_16x16x32_bf16(Al_, Bh[kg], accQ[tt], 0, 0, 0); } }

// counted barrier: drain LDS ops only; global loads stay in flight
#define BARSYNC { asm volatile("s_waitcnt lgkmcnt(0)" ::: "memory"); \
                  __builtin_amdgcn_sched_barrier(0); \
                  __builtin_amdgcn_s_barrier(); }

    // prologue: chunk 0 staged into buf0
    LOADX(0)
    CVT_STORE(0)
    BARSYNC

    // steady state: c = 0..29 (15 even/odd pairs), branch-free bodies
#pragma unroll 1
    for (int cc = 0; cc < 15; ++cc) {
        const int c0 = 2 * cc;
        BLOAD(c0)                              // B first: MFMA waits only on B
        LOADX(c0 + 1)
        MFMA_PHASE(0)
        CVT_STORE(1)
        BARSYNC
        const int c1 = c0 + 1;
        BLOAD(c1)
        LOADX(c1 + 1)
        MFMA_PHASE(1)
        CVT_STORE(0)
        BARSYNC
    }
    // c = 30: compute buf0, stage chunk 31 (xr must be RELOADED - R15 bug was here)
    BLOAD(30)
    LOADX(31)
    MFMA_PHASE(0)
    CVT_STORE(1)
    BARSYNC
    // c = 31
    BLOAD(31)
    MFMA_PHASE(1)
    __syncthreads();                           // full drain before aliasing lm

#undef LOADX
#undef BLOAD
#undef CVT_STORE
#undef MFMA_PHASE
#undef BARSYNC

    // merge logits into aliased LDS
    float* lmf = (float*)smem;                 // [64][68]
#pragma unroll
    for (int tt = 0; tt < 4; ++tt)
#pragma unroll
        for (int jr = 0; jr < 4; ++jr)
            lmf[(tt * 16 + (lane >> 4) * 4 + jr) * 68 + et * 16 + (lane & 15)] =
                accP[tt][jr] + accQ[tt][jr];
    __syncthreads();

    // ---- epilogue: 4 threads per token, 16 experts each ----
    float* mout = out;
    float* wout = out + (size_t)NT * NE;
    float* iout = wout + (size_t)NT * 2;

    const int t   = tid >> 2;                  // local token 0..63
    const int s   = tid & 3;                   // 16-expert segment
    const int tok = t0 + t;

    float vv[16];
#pragma unroll
    for (int j4 = 0; j4 < 4; ++j4) {
        float4 pv = *(const float4*)&lmf[t * 68 + s * 16 + j4 * 4];
        vv[j4 * 4] = pv.x; vv[j4 * 4 + 1] = pv.y; vv[j4 * 4 + 2] = pv.z; vv[j4 * 4 + 3] = pv.w;
    }

    float m1 = -FLT_MAX, m2 = -FLT_MAX, m3 = -FLT_MAX;
    int   i1 = NE, i2 = NE, i3 = NE;
    auto ins = [&](float v, int e) {
        bool b1 = (v > m1) || (v == m1 && e < i1);
        bool b2 = (v > m2) || (v == m2 && e < i2);
        bool b3 = (v > m3) || (v == m3 && e < i3);
        if (b1)      { m3 = m2; i3 = i2; m2 = m1; i2 = i1; m1 = v; i1 = e; }
        else if (b2) { m3 = m2; i3 = i2; m2 = v; i2 = e; }
        else if (b3) { m3 = v; i3 = e; }
    };
#pragma unroll
    for (int j = 0; j < 16; ++j) ins(vv[j], s * 16 + j);
#pragma unroll
    for (int off = 1; off <= 2; off <<= 1) {   // merge across the 4-lane group
        float om1 = __shfl_xor(m1, off, 64); int oi1 = __shfl_xor(i1, off, 64);
        float om2 = __shfl_xor(m2, off, 64); int oi2 = __shfl_xor(i2, off, 64);
        float om3 = __shfl_xor(m3, off, 64); int oi3 = __shfl_xor(i3, off, 64);
        ins(om1, oi1); ins(om2, oi2); ins(om3, oi3);
    }

    float ed  = expf(m2 - m1);
    float inv = 1.f / (1.f + ed);

#pragma unroll
    for (int j4 = 0; j4 < 4; ++j4) {
        float4 mv;
        int e0 = s * 16 + j4 * 4;
        mv.x = (e0     == i1 || e0     == i2) ? 1.f : 0.f;
        mv.y = (e0 + 1 == i1 || e0 + 1 == i2) ? 1.f : 0.f;
        mv.z = (e0 + 2 == i1 || e0 + 2 == i2) ? 1.f : 0.f;
        mv.w = (e0 + 3 == i1 || e0 + 3 == i2) ? 1.f : 0.f;
        *(float4*)(mout + (size_t)tok * NE + e0) = mv;
    }

    if (s == 0) {
        *(float2*)(wout + 2 * tok) = make_float2(inv, ed * inv);
        *(float2*)(iout + 2 * tok) = make_float2((float)i1, (float)i2);
        if ((m1 - m2 < TAU) || (m2 - m3 < TAU)) {
            int slot = atomicAdd(cnt, 1);
            list[slot] = tok;
        }
    }
}

// Exact fp32 recompute of flagged (near-tie) tokens; overwrites their outputs.
__global__ __launch_bounds__(256)
void repair(const float* __restrict__ x, const float* __restrict__ gw,
            float* __restrict__ out, const int* __restrict__ cnt,
            const int* __restrict__ list) {
    __shared__ float red[64][5];
    const int n   = *cnt;
    const int tid = threadIdx.x;
    const int e   = tid & 63, qq = tid >> 6;     // expert, k-quarter

    float* mout = out;
    float* wout = out + (size_t)NT * NE;
    float* iout = wout + (size_t)NT * 2;

    for (int i = blockIdx.x; i < n; i += gridDim.x) {
        const int tok = list[i];
        const float* xr = x + (size_t)tok * DIM + qq * 512;
        const float* wr = gw + (size_t)e * DIM + qq * 512;
        float a = 0.f;
        for (int j = 0; j < 512; j += 4) {
            float4 xv = *(const float4*)(xr + j);
            float4 wv = *(const float4*)(wr + j);
            a = fmaf(xv.x, wv.x, a); a = fmaf(xv.y, wv.y, a);
            a = fmaf(xv.z, wv.z, a); a = fmaf(xv.w, wv.w, a);
        }
        red[e][qq] = a;
        __syncthreads();
        if (tid < 64) {
            float v = ((red[e][0] + red[e][1]) + red[e][2]) + red[e][3];
            float m1 = v, m2 = -FLT_MAX; int i1 = e, i2 = NE;
#pragma unroll
            for (int off = 1; off <= 32; off <<= 1) {
                float om1 = __shfl_xor(m1, off, 64); int oi1 = __shfl_xor(i1, off, 64);
                float om2 = __shfl_xor(m2, off, 64); int oi2 = __shfl_xor(i2, off, 64);
                bool selfFirst = (m1 > om1) || (m1 == om1 && i1 < oi1);
                if (selfFirst) {
                    if (!((m2 > om1) || (m2 == om1 && i2 < oi1))) { m2 = om1; i2 = oi1; }
                } else {
                    bool c = (m1 > om2) || (m1 == om2 && i1 < oi2);
                    if (c) { m2 = m1; i2 = i1; } else { m2 = om2; i2 = oi2; }
                    m1 = om1; i1 = oi1;
                }
            }
            float ed  = expf(m2 - m1);
            float inv = 1.f / (1.f + ed);
            mout[(size_t)tok * NE + e] = (e == i1 || e == i2) ? 1.f : 0.f;
            if (e == 0) {
                *(float2*)(wout + 2 * tok) = make_float2(inv, ed * inv);
                *(float2*)(iout + 2 * tok) = make_float2((float)i1, (float)i2);
            }
        }
        __syncthreads();
    }
}

extern "C" void kernel_launch(void* const* d_in, const int* in_sizes, int n_in,
                              void* d_out, int out_size, void* d_ws, size_t ws_size,
                              hipStream_t stream) {
    const float* x  = (const float*)d_in[0];
    const float* gw = (const float*)d_in[1];
    float* out = (float*)d_out;

    unsigned short* wph = (unsigned short*)d_ws;         // 256 KB (packed hi)
    unsigned short* wpl = wph + (size_t)NE * DIM;        // 256 KB (packed lo)
    int* cnt  = (int*)(wpl + (size_t)NE * DIM);          // 4 B
    int* list = cnt + 1;                                 // 128 KB

    prep_w<<<dim3(64), dim3(256), 0, stream>>>(gw, wph, wpl, cnt);
    router_mfma<<<dim3(NT / 64), dim3(256), 0, stream>>>(x, wph, wpl, out, cnt, list);
    repair<<<dim3(256), dim3(256), 0, stream>>>(x, gw, out, cnt, list);
}

// Round 17
// 108.849 us; speedup vs baseline: 1.0385x; 1.0385x over previous
//
#include <hip/hip_runtime.h>
#include <float.h>

#define NT 32768
#define DIM 2048
#define NE 64
#define TAU 1e-3f
#define CHUNK 64
#define NCH 16              // chunks per k-half (16 x 64 = 1024)

typedef __attribute__((ext_vector_type(8))) short short8;
typedef __attribute__((ext_vector_type(4))) float f32x4;

__device__ __forceinline__ unsigned short f2bf(float f) {
    unsigned u = __float_as_uint(f);
    u += 0x7fffu + ((u >> 16) & 1u);          // RNE
    return (unsigned short)(u >> 16);
}
__device__ __forceinline__ float bf2f(unsigned short h) {
    return __uint_as_float(((unsigned)h) << 16);
}

// Pack gw into MFMA-B fragment order, split hi/lo bf16 (RNE):
// wpk[et][ksg][lane][j] = gw[et*16 + (lane&15)][ksg*32 + (lane>>4)*8 + j]
__global__ __launch_bounds__(256)
void prep_w(const float* __restrict__ gw, unsigned short* __restrict__ wph,
            unsigned short* __restrict__ wpl, int* __restrict__ cnt) {
    const int gid  = blockIdx.x * 256 + threadIdx.x;   // 16384 threads
    const int lane = gid & 63;
    const int ksg  = (gid >> 6) & 63;
    const int et   = gid >> 12;
    const int e    = et * 16 + (lane & 15);
    const int k0   = ksg * 32 + (lane >> 4) * 8;

    float4 v0 = *(const float4*)(gw + (size_t)e * DIM + k0);
    float4 v1 = *(const float4*)(gw + (size_t)e * DIM + k0 + 4);
    float xf[8] = {v0.x, v0.y, v0.z, v0.w, v1.x, v1.y, v1.z, v1.w};
    short8 h, l;
#pragma unroll
    for (int j = 0; j < 8; ++j) {
        unsigned short hh = f2bf(xf[j]);
        h[j] = (short)hh;
        l[j] = (short)f2bf(xf[j] - bf2f(hh));
    }
    *(short8*)(wph + (size_t)gid * 8) = h;
    *(short8*)(wpl + (size_t)gid * 8) = l;
    if (gid == 0) *cnt = 0;
}

__global__ __launch_bounds__(512, 4)
void router_mfma(const float* __restrict__ x,
                 const unsigned short* __restrict__ wph,
                 const unsigned short* __restrict__ wpl,
                 float* __restrict__ out,
                 int* __restrict__ cnt, int* __restrict__ list) {
    // 64 KB: [buf2][kh2][{hi 8K, lo 8K}] bf16 [64 tok][64 k]; epilogue aliases lm[2][64][68]
    __shared__ __align__(16) unsigned char smem[65536];

    const int tid  = threadIdx.x;
    const int lane = tid & 63;
    const int wid  = __builtin_amdgcn_readfirstlane(tid >> 6);
    const int et   = wid & 3;                  // 16-expert tile
    const int kh   = wid >> 2;                 // k-half 0..1
    const int t0   = blockIdx.x * 64;

    // staging: thread -> (k-half khs, row r, k-16-group so); 16 floats each
    const int khs = tid >> 8;                  // 0..1
    const int sr  = tid & 63;
    const int so  = (tid >> 6) & 3;
    const unsigned sw0 = (unsigned)(sr * 128 + (((2 * so)     ^ (sr & 7)) << 4));
    const unsigned sw1 = (unsigned)(sr * 128 + (((2 * so + 1) ^ (sr & 7)) << 4));
    const float* xrow = x + (size_t)(t0 + sr) * DIM + khs * 1024 + so * 16;

    // compute-side read offsets: row = tt*16+(lane&15); slot = (kg*4+(lane>>4)) ^ (lane&7)
    unsigned rbase[4], koff[2];
#pragma unroll
    for (int tt = 0; tt < 4; ++tt)
        rbase[tt] = (unsigned)((tt * 16 + (lane & 15)) * 128);
#pragma unroll
    for (int kg = 0; kg < 2; ++kg)
        koff[kg] = (unsigned)(((kg * 4 + (lane >> 4)) ^ (lane & 7)) << 4);

    f32x4 accP[4], accQ[4];
#pragma unroll
    for (int tt = 0; tt < 4; ++tt)
#pragma unroll
        for (int j = 0; j < 4; ++j) { accP[tt][j] = 0.f; accQ[tt][j] = 0.f; }

    float4 xr[4];                              // 16 floats staged per thread
    short8 Bh0[2], Bl0[2], Bh1[2], Bl1[2];     // B double-bank (prefetch 1 STEP ahead)

#define LOADX(c_) { _Pragma("unroll") for (int i = 0; i < 4; ++i) \
        xr[i] = *(const float4*)(xrow + (c_) * CHUNK + i * 4); }

#define BLOAD(bk_, c_) { _Pragma("unroll") for (int kg = 0; kg < 2; ++kg) { \
        size_t o_ = (((size_t)et * 64 + kh * 32 + ((c_) * 2 + kg)) * 64 + lane) * 8; \
        Bh##bk_[kg] = *(const short8*)(wph + o_); \
        Bl##bk_[kg] = *(const short8*)(wpl + o_); } }

// truncation split: hi = top16(x), lo = top16(x - hi); 2x(16B hi + 16B lo)
#define CVT_STORE(buf_) { \
        _Pragma("unroll") for (int p = 0; p < 2; ++p) { \
            float4 a_ = xr[2*p], b_ = xr[2*p+1]; \
            float f_[8] = {a_.x, a_.y, a_.z, a_.w, b_.x, b_.y, b_.z, b_.w}; \
            unsigned short hh[8], ll[8]; \
            _Pragma("unroll") for (int j = 0; j < 8; ++j) { \
                unsigned u_ = __float_as_uint(f_[j]); \
                hh[j] = (unsigned short)(u_ >> 16); \
                float lo_ = f_[j] - __uint_as_float(u_ & 0xffff0000u); \
                ll[j] = (unsigned short)(__float_as_uint(lo_) >> 16); } \
            unsigned char* p0_ = smem + (buf_) * 32768 + khs * 16384 + (p ? sw1 : sw0); \
            *(ushort4*)p0_ = make_ushort4(hh[0], hh[1], hh[2], hh[3]); \
            *(ushort4*)(p0_ + 8) = make_ushort4(hh[4], hh[5], hh[6], hh[7]); \
            *(ushort4*)(p0_ + 8192) = make_ushort4(ll[0], ll[1], ll[2], ll[3]); \
            *(ushort4*)(p0_ + 8200) = make_ushort4(ll[4], ll[5], ll[6], ll[7]); } }

#define MFMA_PHASE(buf_, bk_) { _Pragma("unroll") for (int kg = 0; kg < 2; ++kg) \
    _Pragma("unroll") for (int tt = 0; tt < 4; ++tt) { \
        const unsigned char* pa_ = smem + (buf_) * 32768 + kh * 16384 + rbase[tt] + koff[kg]; \
        short8 Ah_ = *(const short8*)pa_; \
        short8 Al_ = *(const short8*)(pa_ + 8192); \
        accP[tt] = __builtin_amdgcn_mfma_f32_16x16x32_bf16(Ah_, Bh##bk_[kg], accP[tt], 0, 0, 0); \
        accQ[tt] = __builtin_amdgcn_mfma_f32_16x16x32_bf16(Ah_, Bl##bk_[kg], accQ[tt], 0, 0, 0); \
        accQ[tt] = __builtin_amdgcn_mfma_f32_16x16x32_bf16(Al_, Bh##bk_[kg], accQ[tt], 0, 0, 0); } }

// counted barrier: drain LDS ops only; global loads stay in flight
#define BARSYNC { asm volatile("s_waitcnt lgkmcnt(0)" ::: "memory"); \
                  __builtin_amdgcn_sched_barrier(0); \
                  __builtin_amdgcn_s_barrier(); }

    // prologue: chunk 0 staged -> buf0; B(0) -> bank0
    LOADX(0)
    BLOAD(0, 0)
    CVT_STORE(0)
    BARSYNC

    // steady state: c = 0..13 (7 even/odd pairs), branch-free bodies
    // STEP c: MFMA buf(c&1)/bank(c&1); prefetch B(c+1)->bank((c+1)&1); stage chunk c+1
#pragma unroll 1
    for (int cc = 0; cc < 7; ++cc) {
        const int c0 = 2 * cc;                 // <= 12
        LOADX(c0 + 1)
        BLOAD(1, c0 + 1)
        MFMA_PHASE(0, 0)
        CVT_STORE(1)
        BARSYNC
        const int c1 = c0 + 1;                 // <= 13
        LOADX(c1 + 1)
        BLOAD(0, c1 + 1)
        MFMA_PHASE(1, 1)
        CVT_STORE(0)
        BARSYNC
    }
    // tail c = 14: stage chunk 15 (xr RELOADED - R15 lesson), prefetch B(15)
    LOADX(15)
    BLOAD(1, 15)
    MFMA_PHASE(0, 0)
    CVT_STORE(1)
    BARSYNC
    // tail c = 15
    MFMA_PHASE(1, 1)
    __syncthreads();                           // full drain before aliasing lm

#undef LOADX
#undef BLOAD
#undef CVT_STORE
#undef MFMA_PHASE
#undef BARSYNC

    // merge logits into aliased LDS: lm[kh][64 tok][68]
    float* lmf = (float*)smem;
#pragma unroll
    for (int tt = 0; tt < 4; ++tt)
#pragma unroll
        for (int jr = 0; jr < 4; ++jr)
            lmf[(kh * 64 + tt * 16 + (lane >> 4) * 4 + jr) * 68 + et * 16 + (lane & 15)] =
                accP[tt][jr] + accQ[tt][jr];
    __syncthreads();

    // ---- epilogue: 8 threads per token, 8 experts each; sum the kh-halves ----
    float* mout = out;
    float* wout = out + (size_t)NT * NE;
    float* iout = wout + (size_t)NT * 2;

    const int t   = tid >> 3;                  // local token 0..63
    const int s   = tid & 7;                   // 8-expert segment
    const int tok = t0 + t;

    float vv[8];
    {
        float4 a0 = *(const float4*)&lmf[t * 68 + s * 8];
        float4 a1 = *(const float4*)&lmf[t * 68 + s * 8 + 4];
        float4 b0 = *(const float4*)&lmf[(64 + t) * 68 + s * 8];
        float4 b1 = *(const float4*)&lmf[(64 + t) * 68 + s * 8 + 4];
        vv[0] = a0.x + b0.x; vv[1] = a0.y + b0.y; vv[2] = a0.z + b0.z; vv[3] = a0.w + b0.w;
        vv[4] = a1.x + b1.x; vv[5] = a1.y + b1.y; vv[6] = a1.z + b1.z; vv[7] = a1.w + b1.w;
    }

    float m1 = -FLT_MAX, m2 = -FLT_MAX, m3 = -FLT_MAX;
    int   i1 = NE, i2 = NE, i3 = NE;
    auto ins = [&](float v, int e) {
        bool b1 = (v > m1) || (v == m1 && e < i1);
        bool b2 = (v > m2) || (v == m2 && e < i2);
        bool b3 = (v > m3) || (v == m3 && e < i3);
        if (b1)      { m3 = m2; i3 = i2; m2 = m1; i2 = i1; m1 = v; i1 = e; }
        else if (b2) { m3 = m2; i3 = i2; m2 = v; i2 = e; }
        else if (b3) { m3 = v; i3 = e; }
    };
#pragma unroll
    for (int j = 0; j < 8; ++j) ins(vv[j], s * 8 + j);
#pragma unroll
    for (int off = 1; off <= 4; off <<= 1) {   // merge across the 8-lane group
        float om1 = __shfl_xor(m1, off, 64); int oi1 = __shfl_xor(i1, off, 64);
        float om2 = __shfl_xor(m2, off, 64); int oi2 = __shfl_xor(i2, off, 64);
        float om3 = __shfl_xor(m3, off, 64); int oi3 = __shfl_xor(i3, off, 64);
        ins(om1, oi1); ins(om2, oi2); ins(om3, oi3);
    }

    float ed  = expf(m2 - m1);
    float inv = 1.f / (1.f + ed);

    {
        float4 mv0, mv1;
        int e0 = s * 8;
        mv0.x = (e0     == i1 || e0     == i2) ? 1.f : 0.f;
        mv0.y = (e0 + 1 == i1 || e0 + 1 == i2) ? 1.f : 0.f;
        mv0.z = (e0 + 2 == i1 || e0 + 2 == i2) ? 1.f : 0.f;
        mv0.w = (e0 + 3 == i1 || e0 + 3 == i2) ? 1.f : 0.f;
        mv1.x = (e0 + 4 == i1 || e0 + 4 == i2) ? 1.f : 0.f;
        mv1.y = (e0 + 5 == i1 || e0 + 5 == i2) ? 1.f : 0.f;
        mv1.z = (e0 + 6 == i1 || e0 + 6 == i2) ? 1.f : 0.f;
        mv1.w = (e0 + 7 == i1 || e0 + 7 == i2) ? 1.f : 0.f;
        *(float4*)(mout + (size_t)tok * NE + e0)     = mv0;
        *(float4*)(mout + (size_t)tok * NE + e0 + 4) = mv1;
    }

    if (s == 0) {
        *(float2*)(wout + 2 * tok) = make_float2(inv, ed * inv);
        *(float2*)(iout + 2 * tok) = make_float2((float)i1, (float)i2);
        if ((m1 - m2 < TAU) || (m2 - m3 < TAU)) {
            int slot = atomicAdd(cnt, 1);
            list[slot] = tok;
        }
    }
}

// Exact fp32 recompute of flagged (near-tie) tokens; overwrites their outputs.
__global__ __launch_bounds__(256)
void repair(const float* __restrict__ x, const float* __restrict__ gw,
            float* __restrict__ out, const int* __restrict__ cnt,
            const int* __restrict__ list) {
    __shared__ float red[64][5];
    const int n   = *cnt;
    const int tid = threadIdx.x;
    const int e   = tid & 63, qq = tid >> 6;     // expert, k-quarter

    float* mout = out;
    float* wout = out + (size_t)NT * NE;
    float* iout = wout + (size_t)NT * 2;

    for (int i = blockIdx.x; i < n; i += gridDim.x) {
        const int tok = list[i];
        const float* xr = x + (size_t)tok * DIM + qq * 512;
        const float* wr = gw + (size_t)e * DIM + qq * 512;
        float a = 0.f;
        for (int j = 0; j < 512; j += 4) {
            float4 xv = *(const float4*)(xr + j);
            float4 wv = *(const float4*)(wr + j);
            a = fmaf(xv.x, wv.x, a); a = fmaf(xv.y, wv.y, a);
            a = fmaf(xv.z, wv.z, a); a = fmaf(xv.w, wv.w, a);
        }
        red[e][qq] = a;
        __syncthreads();
        if (tid < 64) {
            float v = ((red[e][0] + red[e][1]) + red[e][2]) + red[e][3];
            float m1 = v, m2 = -FLT_MAX; int i1 = e, i2 = NE;
#pragma unroll
            for (int off = 1; off <= 32; off <<= 1) {
                float om1 = __shfl_xor(m1, off, 64); int oi1 = __shfl_xor(i1, off, 64);
                float om2 = __shfl_xor(m2, off, 64); int oi2 = __shfl_xor(i2, off, 64);
                bool selfFirst = (m1 > om1) || (m1 == om1 && i1 < oi1);
                if (selfFirst) {
                    if (!((m2 > om1) || (m2 == om1 && i2 < oi1))) { m2 = om1; i2 = oi1; }
                } else {
                    bool c = (m1 > om2) || (m1 == om2 && i1 < oi2);
                    if (c) { m2 = m1; i2 = i1; } else { m2 = om2; i2 = oi2; }
                    m1 = om1; i1 = oi1;
                }
            }
            float ed  = expf(m2 - m1);
            float inv = 1.f / (1.f + ed);
            mout[(size_t)tok * NE + e] = (e == i1 || e == i2) ? 1.f : 0.f;
            if (e == 0) {
                *(float2*)(wout + 2 * tok) = make_float2(inv, ed * inv);
                *(float2*)(iout + 2 * tok) = make_float2((float)i1, (float)i2);
            }
        }
        __syncthreads();
    }
}

extern "C" void kernel_launch(void* const* d_in, const int* in_sizes, int n_in,
                              void* d_out, int out_size, void* d_ws, size_t ws_size,
                              hipStream_t stream) {
    const float* x  = (const float*)d_in[0];
    const float* gw = (const float*)d_in[1];
    float* out = (float*)d_out;

    unsigned short* wph = (unsigned short*)d_ws;         // 256 KB (packed hi)
    unsigned short* wpl = wph + (size_t)NE * DIM;        // 256 KB (packed lo)
    int* cnt  = (int*)(wpl + (size_t)NE * DIM);          // 4 B
    int* list = cnt + 1;                                 // 128 KB

    prep_w<<<dim3(64), dim3(256), 0, stream>>>(gw, wph, wpl, cnt);
    router_mfma<<<dim3(NT / 64), dim3(512), 0, stream>>>(x, wph, wpl, out, cnt, list);
    repair<<<dim3(256), dim3(256), 0, stream>>>(x, gw, out, cnt, list);
}